// Round 1
// baseline (185.368 us; speedup 1.0000x reference)
//
#include <hip/hip_runtime.h>

// ---------------------------------------------------------------------------
// LModel15: edge sampling + bilinear similarity loss (MI355X / gfx950)
// Outputs: [similarity_loss, normal_loss, normalization_loss] (3x fp32)
// ---------------------------------------------------------------------------

constexpr int NVS   = 10;     // NV samples along 'up'
constexpr int IMG_H = 2000;
constexpr int IMG_W = 3000;

struct Geom {
    float p0x, p0y, p0z;
    float p1x, p1y, p1z;
    float p2x, p2y, p2z;
    float p3x, p3y, p3z;
    float cdx, cdy, cdz;   // cur_dir (normalized)
    float cnx, cny, cnz;   // cur_normal (normalized, flipped)
    float cux, cuy, cuz;   // cur_up (normalized)
    float len;             // cur_length
    int   nh;
};

__device__ __forceinline__ Geom compute_geom(const float* __restrict__ ep, int e) {
    Geom g;
    const float* p = ep + (size_t)e * 12;
    g.p0x = p[0];  g.p0y = p[1];  g.p0z = p[2];
    g.p1x = p[3];  g.p1y = p[4];  g.p1z = p[5];
    g.p2x = p[6];  g.p2y = p[7];  g.p2z = p[8];
    g.p3x = p[9];  g.p3y = p[10]; g.p3z = p[11];

    float dx = g.p1x - g.p0x, dy = g.p1y - g.p0y, dz = g.p1z - g.p0z;
    float ax = dx + 1e-6f, ay = dy + 1e-6f, az = dz + 1e-6f;
    g.len = sqrtf(ax * ax + ay * ay + az * az);
    g.cdx = dx / g.len; g.cdy = dy / g.len; g.cdz = dz / g.len;

    float ndx = g.p3x - g.p1x, ndy = g.p3y - g.p1y, ndz = g.p3z - g.p1z;
    // cur_normal = normalize(cross(cur_dir, next_dir))
    float cnx = g.cdy * ndz - g.cdz * ndy;
    float cny = g.cdz * ndx - g.cdx * ndz;
    float cnz = g.cdx * ndy - g.cdy * ndx;
    float n1 = sqrtf(cnx * cnx + cny * cny + cnz * cnz) + 1e-8f;
    cnx /= n1; cny /= n1; cnz /= n1;
    if (cnz > 0.f) { cnx = -cnx; cny = -cny; cnz = -cnz; }
    g.cnx = cnx; g.cny = cny; g.cnz = cnz;

    // cur_up = normalize(cross(cur_normal, cur_dir))
    float cux = cny * g.cdz - cnz * g.cdy;
    float cuy = cnz * g.cdx - cnx * g.cdz;
    float cuz = cnx * g.cdy - cny * g.cdx;
    float n2 = sqrtf(cux * cux + cuy * cuy + cuz * cuz) + 1e-8f;
    g.cux = cux / n2; g.cuy = cuy / n2; g.cuz = cuz / n2;

    int nh = (int)floorf(g.len / 0.05f);
    g.nh = nh < 2 ? 2 : (nh > 1000 ? 1000 : nh);
    return g;
}

__device__ __forceinline__ double block_reduce_d(double v) {
    __shared__ double sh[256];
    int tid = threadIdx.x;
    sh[tid] = v;
    __syncthreads();
    for (int s = 128; s > 0; s >>= 1) {
        if (tid < s) sh[tid] += sh[tid + s];
        __syncthreads();
    }
    double r = sh[0];
    __syncthreads();
    return r;
}

// ---------------------------------------------------------------------------
// setup: zero counters, compute transform = K2h @ E2 @ inv(E1) (double, GJ)
// ---------------------------------------------------------------------------
__global__ void setup_kernel(const float* __restrict__ K2,
                             const float* __restrict__ E1,
                             const float* __restrict__ E2,
                             float* __restrict__ tf,
                             unsigned long long* __restrict__ total_x) {
    if (threadIdx.x != 0 || blockIdx.x != 0) return;
    *total_x = 0ull;

    // Gauss-Jordan inverse of E1 in double
    double a[4][8];
    for (int r = 0; r < 4; ++r)
        for (int c = 0; c < 4; ++c) {
            a[r][c] = (double)E1[r * 4 + c];
            a[r][4 + c] = (r == c) ? 1.0 : 0.0;
        }
    for (int col = 0; col < 4; ++col) {
        int piv = col; double best = fabs(a[col][col]);
        for (int r = col + 1; r < 4; ++r) {
            double t = fabs(a[r][col]);
            if (t > best) { best = t; piv = r; }
        }
        if (piv != col)
            for (int c = 0; c < 8; ++c) { double t = a[col][c]; a[col][c] = a[piv][c]; a[piv][c] = t; }
        double d = a[col][col];
        for (int c = 0; c < 8; ++c) a[col][c] /= d;
        for (int r = 0; r < 4; ++r) {
            if (r == col) continue;
            double f = a[r][col];
            for (int c = 0; c < 8; ++c) a[r][c] -= f * a[col][c];
        }
    }
    double inv1[4][4];
    for (int r = 0; r < 4; ++r)
        for (int c = 0; c < 4; ++c) inv1[r][c] = a[r][4 + c];

    double k2h[4][4];
    for (int r = 0; r < 4; ++r)
        for (int c = 0; c < 4; ++c) k2h[r][c] = (r == c) ? 1.0 : 0.0;
    for (int r = 0; r < 3; ++r)
        for (int c = 0; c < 3; ++c) k2h[r][c] = (double)K2[r * 3 + c];

    double m1[4][4]; // E2 @ inv1
    for (int r = 0; r < 4; ++r)
        for (int c = 0; c < 4; ++c) {
            double s = 0.0;
            for (int k = 0; k < 4; ++k) s += (double)E2[r * 4 + k] * inv1[k][c];
            m1[r][c] = s;
        }
    for (int r = 0; r < 4; ++r)
        for (int c = 0; c < 4; ++c) {
            double s = 0.0;
            for (int k = 0; k < 4; ++k) s += k2h[r][k] * m1[k][c];
            tf[r * 4 + c] = (float)s;
        }
}

// ---------------------------------------------------------------------------
// per-edge losses + total_x
// ---------------------------------------------------------------------------
__global__ __launch_bounds__(256) void edge_kernel(
        const float* __restrict__ ep, int E,
        double* __restrict__ normal_part,
        double* __restrict__ norz_part,
        unsigned long long* __restrict__ total_x) {
    int e = blockIdx.x * blockDim.x + threadIdx.x;
    double t1 = 0.0, t2 = 0.0;
    if (e < E) {
        Geom g = compute_geom(ep, e);
        // prev_normal = normalize(cross(prev_dir, cur_dir))
        float pdx = g.p0x - g.p2x, pdy = g.p0y - g.p2y, pdz = g.p0z - g.p2z;
        float pnx = pdy * g.cdz - pdz * g.cdy;
        float pny = pdz * g.cdx - pdx * g.cdz;
        float pnz = pdx * g.cdy - pdy * g.cdx;
        float n = sqrtf(pnx * pnx + pny * pny + pnz * pnz) + 1e-8f;
        pnx /= n; pny /= n; pnz /= n;
        float dotn = g.cnx * pnx + g.cny * pny + g.cnz * pnz;
        t1 = (double)(1.0f - dotn);

        // observing_normal = normalize(cross(p0, p1))
        float ox = g.p0y * g.p1z - g.p0z * g.p1y;
        float oy = g.p0z * g.p1x - g.p0x * g.p1z;
        float oz = g.p0x * g.p1y - g.p0y * g.p1x;
        float no = sqrtf(ox * ox + oy * oy + oz * oz) + 1e-8f;
        ox /= no; oy /= no; oz /= no;
        float snp = fminf(fabsf(g.cux * ox + g.cuy * oy + g.cuz * oz), 0.5f);
        t2 = (double)(1.0f - snp / 0.5f);

        atomicAdd(total_x, (unsigned long long)g.nh);
    }
    double s1 = block_reduce_d(t1);
    double s2 = block_reduce_d(t2);
    if (threadIdx.x == 0) {
        normal_part[blockIdx.x] = s1;
        norz_part[blockIdx.x]   = s2;
    }
}

// ---------------------------------------------------------------------------
// bilinear sample of a CHW fp32 image (3 channels)
// ---------------------------------------------------------------------------
__device__ __forceinline__ void bilinear3(const float* __restrict__ img,
                                          float u, float v,
                                          float& r, float& g, float& b) {
    float x = u * (float)IMG_W - 0.5f;
    float y = v * (float)IMG_H - 0.5f;
    float x0 = floorf(x), y0 = floorf(y);
    float wx = x - x0, wy = y - y0;
    int x0i = (int)x0; x0i = x0i < 0 ? 0 : (x0i > IMG_W - 1 ? IMG_W - 1 : x0i);
    int x1i = x0i + 1; x1i = x1i > IMG_W - 1 ? IMG_W - 1 : x1i;
    int y0i = (int)y0; y0i = y0i < 0 ? 0 : (y0i > IMG_H - 1 ? IMG_H - 1 : y0i);
    int y1i = y0i + 1; y1i = y1i > IMG_H - 1 ? IMG_H - 1 : y1i;
    float w00 = (1.f - wx) * (1.f - wy);
    float w10 = wx * (1.f - wy);
    float w01 = (1.f - wx) * wy;
    float w11 = wx * wy;
    float out[3];
#pragma unroll
    for (int c = 0; c < 3; ++c) {
        const float* p = img + (size_t)c * (size_t)IMG_H * (size_t)IMG_W;
        float v00 = p[(size_t)y0i * IMG_W + x0i];
        float v10 = p[(size_t)y0i * IMG_W + x1i];
        float v01 = p[(size_t)y1i * IMG_W + x0i];
        float v11 = p[(size_t)y1i * IMG_W + x1i];
        out[c] = v00 * w00 + v10 * w10 + v01 * w01 + v11 * w11;
    }
    r = out[0]; g = out[1]; b = out[2];
}

// ---------------------------------------------------------------------------
// main sampling kernel: one block per edge
// ---------------------------------------------------------------------------
__global__ __launch_bounds__(256) void sample_kernel(
        const float* __restrict__ ep,
        const float* __restrict__ img1,
        const float* __restrict__ img2,
        const float* __restrict__ K1,
        const float* __restrict__ tf,
        double* __restrict__ sim_part) {
    int e = blockIdx.x;
    Geom g = compute_geom(ep, e);

    float k00 = K1[0], k01 = K1[1], k02 = K1[2];
    float k10 = K1[3], k11 = K1[4], k12 = K1[5];
    float k20 = K1[6], k21 = K1[7], k22 = K1[8];
    float t00 = tf[0],  t01 = tf[1],  t02 = tf[2],  t03 = tf[3];
    float t10 = tf[4],  t11 = tf[5],  t12 = tf[6],  t13 = tf[7];
    float t20 = tf[8],  t21 = tf[9],  t22 = tf[10], t23 = tf[11];

    int ns = g.nh * NVS;
    float fnh1 = (float)(g.nh - 1);
    double lsum = 0.0;

    for (int s = threadIdx.x; s < ns; s += blockDim.x) {
        int i = s / NVS;
        int j = s - i * NVS;
        float dxv = ((float)i / fnh1) * g.len;
        float dyv = ((float)j / 9.0f) * 0.5f;

        float px = g.cdx * dxv + g.cux * dyv + g.p0x;
        float py = g.cdy * dxv + g.cuy * dyv + g.p0y;
        float pz = g.cdz * dxv + g.cuz * dyv + g.p0z;

        // proj 1
        float w1 = k20 * px + k21 * py + k22 * pz;
        float u1 = (k00 * px + k01 * py + k02 * pz) / w1;
        float v1 = (k10 * px + k11 * py + k12 * pz) / w1;
        u1 = fminf(fmaxf(u1, 0.f), 0.999999f);
        v1 = fminf(fmaxf(v1, 0.f), 0.999999f);
        float s1r, s1g, s1b;
        bilinear3(img1, u1, v1, s1r, s1g, s1b);

        // proj 2
        float w2 = t20 * px + t21 * py + t22 * pz + t23;
        float u2 = (t00 * px + t01 * py + t02 * pz + t03) / w2;
        float v2 = (t10 * px + t11 * py + t12 * pz + t13) / w2;
        u2 = fminf(fmaxf(u2, 0.f), 0.999999f);
        v2 = fminf(fmaxf(v2, 0.f), 0.999999f);
        float s2r, s2g, s2b;
        bilinear3(img2, u2, v2, s2r, s2g, s2b);

        float dr = s1r - s2r, dg = s1g - s2g, db = s1b - s2b;
        lsum += (double)(dr * dr) + (double)(dg * dg) + (double)(db * db);
    }

    double tot = block_reduce_d(lsum);
    if (threadIdx.x == 0) sim_part[blockIdx.x] = tot;
}

// ---------------------------------------------------------------------------
// finalize: deterministic reduction of partials, write 3 outputs
// ---------------------------------------------------------------------------
__global__ __launch_bounds__(256) void finalize_kernel(
        const double* __restrict__ sim_part, int n_sim,
        const double* __restrict__ normal_part,
        const double* __restrict__ norz_part, int n_a,
        const unsigned long long* __restrict__ total_x,
        float* __restrict__ out, int E) {
    int tid = threadIdx.x;
    double s = 0.0;
    for (int i = tid; i < n_sim; i += 256) s += sim_part[i];
    double sim = block_reduce_d(s);

    s = 0.0;
    for (int i = tid; i < n_a; i += 256) s += normal_part[i];
    double nrm = block_reduce_d(s);

    s = 0.0;
    for (int i = tid; i < n_a; i += 256) s += norz_part[i];
    double nz = block_reduce_d(s);

    if (tid == 0) {
        double total = (double)(*total_x) * (double)NVS * 3.0;
        out[0] = (float)(sim / total);
        out[1] = (float)((nrm / (double)E) * 0.5);
        out[2] = (float)(nz / (double)E);
    }
}

// ---------------------------------------------------------------------------
extern "C" void kernel_launch(void* const* d_in, const int* in_sizes, int n_in,
                              void* d_out, int out_size, void* d_ws, size_t ws_size,
                              hipStream_t stream) {
    const float* ep  = (const float*)d_in[0];
    const float* im1 = (const float*)d_in[1];
    const float* im2 = (const float*)d_in[2];
    const float* K1  = (const float*)d_in[3];
    const float* K2  = (const float*)d_in[4];
    const float* E1  = (const float*)d_in[5];
    const float* E2  = (const float*)d_in[6];
    float* out = (float*)d_out;

    int E = in_sizes[0] / 12;
    int nA = (E + 255) / 256;

    char* ws = (char*)d_ws;
    double* sim_part    = (double*)ws;                           // E doubles
    double* normal_part = (double*)(ws + (size_t)E * 8);         // nA doubles
    double* norz_part   = normal_part + nA;                      // nA doubles
    unsigned long long* total_x = (unsigned long long*)(norz_part + nA);
    float* tf = (float*)(total_x + 1);                           // 16 floats

    setup_kernel<<<1, 64, 0, stream>>>(K2, E1, E2, tf, total_x);
    edge_kernel<<<nA, 256, 0, stream>>>(ep, E, normal_part, norz_part, total_x);
    sample_kernel<<<E, 256, 0, stream>>>(ep, im1, im2, K1, tf, sim_part);
    finalize_kernel<<<1, 256, 0, stream>>>(sim_part, E, normal_part, norz_part, nA,
                                           total_x, out, E);
}

// Round 2
// 109.095 us; speedup vs baseline: 1.6991x; 1.6991x over previous
//
#include <hip/hip_runtime.h>
#include <hip/hip_fp16.h>

// ---------------------------------------------------------------------------
// LModel15: edge sampling + bilinear similarity loss (MI355X / gfx950)
// Outputs: [similarity_loss, normal_loss, normalization_loss] (3x fp32)
// R2: repack CHW fp32 images -> HWC fp16-RGBA (8B/pixel) in ws, sample packed.
// ---------------------------------------------------------------------------

constexpr int NVS   = 10;     // NV samples along 'up'
constexpr int IMG_H = 2000;
constexpr int IMG_W = 3000;
constexpr int NPIX  = IMG_H * IMG_W;

struct Geom {
    float p0x, p0y, p0z;
    float p1x, p1y, p1z;
    float p2x, p2y, p2z;
    float p3x, p3y, p3z;
    float cdx, cdy, cdz;   // cur_dir (normalized)
    float cnx, cny, cnz;   // cur_normal (normalized, flipped)
    float cux, cuy, cuz;   // cur_up (normalized)
    float len;             // cur_length
    int   nh;
};

__device__ __forceinline__ Geom compute_geom(const float* __restrict__ ep, int e) {
    Geom g;
    const float* p = ep + (size_t)e * 12;
    g.p0x = p[0];  g.p0y = p[1];  g.p0z = p[2];
    g.p1x = p[3];  g.p1y = p[4];  g.p1z = p[5];
    g.p2x = p[6];  g.p2y = p[7];  g.p2z = p[8];
    g.p3x = p[9];  g.p3y = p[10]; g.p3z = p[11];

    float dx = g.p1x - g.p0x, dy = g.p1y - g.p0y, dz = g.p1z - g.p0z;
    float ax = dx + 1e-6f, ay = dy + 1e-6f, az = dz + 1e-6f;
    g.len = sqrtf(ax * ax + ay * ay + az * az);
    g.cdx = dx / g.len; g.cdy = dy / g.len; g.cdz = dz / g.len;

    float ndx = g.p3x - g.p1x, ndy = g.p3y - g.p1y, ndz = g.p3z - g.p1z;
    float cnx = g.cdy * ndz - g.cdz * ndy;
    float cny = g.cdz * ndx - g.cdx * ndz;
    float cnz = g.cdx * ndy - g.cdy * ndx;
    float n1 = sqrtf(cnx * cnx + cny * cny + cnz * cnz) + 1e-8f;
    cnx /= n1; cny /= n1; cnz /= n1;
    if (cnz > 0.f) { cnx = -cnx; cny = -cny; cnz = -cnz; }
    g.cnx = cnx; g.cny = cny; g.cnz = cnz;

    float cux = cny * g.cdz - cnz * g.cdy;
    float cuy = cnz * g.cdx - cnx * g.cdz;
    float cuz = cnx * g.cdy - cny * g.cdx;
    float n2 = sqrtf(cux * cux + cuy * cuy + cuz * cuz) + 1e-8f;
    g.cux = cux / n2; g.cuy = cuy / n2; g.cuz = cuz / n2;

    int nh = (int)floorf(g.len / 0.05f);
    g.nh = nh < 2 ? 2 : (nh > 1000 ? 1000 : nh);
    return g;
}

__device__ __forceinline__ double block_reduce_d(double v) {
    __shared__ double sh[256];
    int tid = threadIdx.x;
    sh[tid] = v;
    __syncthreads();
    for (int s = 128; s > 0; s >>= 1) {
        if (tid < s) sh[tid] += sh[tid + s];
        __syncthreads();
    }
    double r = sh[0];
    __syncthreads();
    return r;
}

// ---------------------------------------------------------------------------
// setup: zero counters, compute transform = K2h @ E2 @ inv(E1) (double, GJ)
// ---------------------------------------------------------------------------
__global__ void setup_kernel(const float* __restrict__ K2,
                             const float* __restrict__ E1,
                             const float* __restrict__ E2,
                             float* __restrict__ tf,
                             unsigned long long* __restrict__ total_x) {
    if (threadIdx.x != 0 || blockIdx.x != 0) return;
    *total_x = 0ull;

    double a[4][8];
    for (int r = 0; r < 4; ++r)
        for (int c = 0; c < 4; ++c) {
            a[r][c] = (double)E1[r * 4 + c];
            a[r][4 + c] = (r == c) ? 1.0 : 0.0;
        }
    for (int col = 0; col < 4; ++col) {
        int piv = col; double best = fabs(a[col][col]);
        for (int r = col + 1; r < 4; ++r) {
            double t = fabs(a[r][col]);
            if (t > best) { best = t; piv = r; }
        }
        if (piv != col)
            for (int c = 0; c < 8; ++c) { double t = a[col][c]; a[col][c] = a[piv][c]; a[piv][c] = t; }
        double d = a[col][col];
        for (int c = 0; c < 8; ++c) a[col][c] /= d;
        for (int r = 0; r < 4; ++r) {
            if (r == col) continue;
            double f = a[r][col];
            for (int c = 0; c < 8; ++c) a[r][c] -= f * a[col][c];
        }
    }
    double inv1[4][4];
    for (int r = 0; r < 4; ++r)
        for (int c = 0; c < 4; ++c) inv1[r][c] = a[r][4 + c];

    double k2h[4][4];
    for (int r = 0; r < 4; ++r)
        for (int c = 0; c < 4; ++c) k2h[r][c] = (r == c) ? 1.0 : 0.0;
    for (int r = 0; r < 3; ++r)
        for (int c = 0; c < 3; ++c) k2h[r][c] = (double)K2[r * 3 + c];

    double m1[4][4];
    for (int r = 0; r < 4; ++r)
        for (int c = 0; c < 4; ++c) {
            double s = 0.0;
            for (int k = 0; k < 4; ++k) s += (double)E2[r * 4 + k] * inv1[k][c];
            m1[r][c] = s;
        }
    for (int r = 0; r < 4; ++r)
        for (int c = 0; c < 4; ++c) {
            double s = 0.0;
            for (int k = 0; k < 4; ++k) s += k2h[r][k] * m1[k][c];
            tf[r * 4 + c] = (float)s;
        }
}

// ---------------------------------------------------------------------------
// per-edge losses + total_x
// ---------------------------------------------------------------------------
__global__ __launch_bounds__(256) void edge_kernel(
        const float* __restrict__ ep, int E,
        double* __restrict__ normal_part,
        double* __restrict__ norz_part,
        unsigned long long* __restrict__ total_x) {
    int e = blockIdx.x * blockDim.x + threadIdx.x;
    double t1 = 0.0, t2 = 0.0;
    if (e < E) {
        Geom g = compute_geom(ep, e);
        float pdx = g.p0x - g.p2x, pdy = g.p0y - g.p2y, pdz = g.p0z - g.p2z;
        float pnx = pdy * g.cdz - pdz * g.cdy;
        float pny = pdz * g.cdx - pdx * g.cdz;
        float pnz = pdx * g.cdy - pdy * g.cdx;
        float n = sqrtf(pnx * pnx + pny * pny + pnz * pnz) + 1e-8f;
        pnx /= n; pny /= n; pnz /= n;
        float dotn = g.cnx * pnx + g.cny * pny + g.cnz * pnz;
        t1 = (double)(1.0f - dotn);

        float ox = g.p0y * g.p1z - g.p0z * g.p1y;
        float oy = g.p0z * g.p1x - g.p0x * g.p1z;
        float oz = g.p0x * g.p1y - g.p0y * g.p1x;
        float no = sqrtf(ox * ox + oy * oy + oz * oz) + 1e-8f;
        ox /= no; oy /= no; oz /= no;
        float snp = fminf(fabsf(g.cux * ox + g.cuy * oy + g.cuz * oz), 0.5f);
        t2 = (double)(1.0f - snp / 0.5f);

        atomicAdd(total_x, (unsigned long long)g.nh);
    }
    double s1 = block_reduce_d(t1);
    double s2 = block_reduce_d(t2);
    if (threadIdx.x == 0) {
        normal_part[blockIdx.x] = s1;
        norz_part[blockIdx.x]   = s2;
    }
}

// ---------------------------------------------------------------------------
// repack: CHW fp32 (3 planes) -> HWC fp16-RGBA (uint2 = 8B per pixel)
// 4 pixels per thread: 3x float4 loads, 2x uint4 stores.
// ---------------------------------------------------------------------------
__device__ __forceinline__ unsigned pack2h(float a, float b) {
    __half2 h = __floats2half2_rn(a, b);
    return *reinterpret_cast<unsigned*>(&h);
}

__global__ __launch_bounds__(256) void repack_kernel(
        const float* __restrict__ img1, const float* __restrict__ img2,
        uint2* __restrict__ o1, uint2* __restrict__ o2) {
    const int nq = NPIX / 4;  // quads per image
    int stride = gridDim.x * blockDim.x;
    for (int idx = blockIdx.x * blockDim.x + threadIdx.x; idx < 2 * nq; idx += stride) {
        const float* img;
        uint2* out;
        int q;
        if (idx < nq) { img = img1; out = o1; q = idx; }
        else          { img = img2; out = o2; q = idx - nq; }
        float4 r = reinterpret_cast<const float4*>(img)[q];
        float4 g = reinterpret_cast<const float4*>(img + NPIX)[q];
        float4 b = reinterpret_cast<const float4*>(img + 2 * (size_t)NPIX)[q];
        uint4 lo, hi;
        lo.x = pack2h(r.x, g.x); lo.y = pack2h(b.x, 0.f);
        lo.z = pack2h(r.y, g.y); lo.w = pack2h(b.y, 0.f);
        hi.x = pack2h(r.z, g.z); hi.y = pack2h(b.z, 0.f);
        hi.z = pack2h(r.w, g.w); hi.w = pack2h(b.w, 0.f);
        reinterpret_cast<uint4*>(out)[q * 2]     = lo;
        reinterpret_cast<uint4*>(out)[q * 2 + 1] = hi;
    }
}

// ---------------------------------------------------------------------------
// bilinear sample of packed fp16-RGBA image: 4x 8B gathers
// ---------------------------------------------------------------------------
__device__ __forceinline__ void bilinear3h(const uint2* __restrict__ img,
                                           float u, float v,
                                           float& r, float& g, float& b) {
    float x = u * (float)IMG_W - 0.5f;
    float y = v * (float)IMG_H - 0.5f;
    float x0 = floorf(x), y0 = floorf(y);
    float wx = x - x0, wy = y - y0;
    int x0i = (int)x0; x0i = x0i < 0 ? 0 : (x0i > IMG_W - 1 ? IMG_W - 1 : x0i);
    int x1i = x0i + 1; x1i = x1i > IMG_W - 1 ? IMG_W - 1 : x1i;
    int y0i = (int)y0; y0i = y0i < 0 ? 0 : (y0i > IMG_H - 1 ? IMG_H - 1 : y0i);
    int y1i = y0i + 1; y1i = y1i > IMG_H - 1 ? IMG_H - 1 : y1i;
    float w00 = (1.f - wx) * (1.f - wy);
    float w10 = wx * (1.f - wy);
    float w01 = (1.f - wx) * wy;
    float w11 = wx * wy;

    uint2 t00 = img[(size_t)y0i * IMG_W + x0i];
    uint2 t10 = img[(size_t)y0i * IMG_W + x1i];
    uint2 t01 = img[(size_t)y1i * IMG_W + x0i];
    uint2 t11 = img[(size_t)y1i * IMG_W + x1i];

    float racc = 0.f, gacc = 0.f, bacc = 0.f;
    auto acc = [&](uint2 t, float w) {
        __half2 h1 = *reinterpret_cast<__half2*>(&t.x);
        __half2 h2 = *reinterpret_cast<__half2*>(&t.y);
        float2 f1 = __half22float2(h1);
        float2 f2 = __half22float2(h2);
        racc += w * f1.x; gacc += w * f1.y; bacc += w * f2.x;
    };
    acc(t00, w00); acc(t10, w10); acc(t01, w01); acc(t11, w11);
    r = racc; g = gacc; b = bacc;
}

// fp32 CHW fallback (used only when ws is too small to hold packed images)
__device__ __forceinline__ void bilinear3(const float* __restrict__ img,
                                          float u, float v,
                                          float& r, float& g, float& b) {
    float x = u * (float)IMG_W - 0.5f;
    float y = v * (float)IMG_H - 0.5f;
    float x0 = floorf(x), y0 = floorf(y);
    float wx = x - x0, wy = y - y0;
    int x0i = (int)x0; x0i = x0i < 0 ? 0 : (x0i > IMG_W - 1 ? IMG_W - 1 : x0i);
    int x1i = x0i + 1; x1i = x1i > IMG_W - 1 ? IMG_W - 1 : x1i;
    int y0i = (int)y0; y0i = y0i < 0 ? 0 : (y0i > IMG_H - 1 ? IMG_H - 1 : y0i);
    int y1i = y0i + 1; y1i = y1i > IMG_H - 1 ? IMG_H - 1 : y1i;
    float w00 = (1.f - wx) * (1.f - wy);
    float w10 = wx * (1.f - wy);
    float w01 = (1.f - wx) * wy;
    float w11 = wx * wy;
    float out[3];
#pragma unroll
    for (int c = 0; c < 3; ++c) {
        const float* p = img + (size_t)c * NPIX;
        float v00 = p[(size_t)y0i * IMG_W + x0i];
        float v10 = p[(size_t)y0i * IMG_W + x1i];
        float v01 = p[(size_t)y1i * IMG_W + x0i];
        float v11 = p[(size_t)y1i * IMG_W + x1i];
        out[c] = v00 * w00 + v10 * w10 + v01 * w01 + v11 * w11;
    }
    r = out[0]; g = out[1]; b = out[2];
}

// ---------------------------------------------------------------------------
// main sampling kernels: one block per edge
// ---------------------------------------------------------------------------
template <bool PACKED>
__global__ __launch_bounds__(256) void sample_kernel_t(
        const float* __restrict__ ep,
        const void* __restrict__ img1,
        const void* __restrict__ img2,
        const float* __restrict__ K1,
        const float* __restrict__ tf,
        double* __restrict__ sim_part) {
    int e = blockIdx.x;
    Geom g = compute_geom(ep, e);

    float k00 = K1[0], k01 = K1[1], k02 = K1[2];
    float k10 = K1[3], k11 = K1[4], k12 = K1[5];
    float k20 = K1[6], k21 = K1[7], k22 = K1[8];
    float t00 = tf[0],  t01 = tf[1],  t02 = tf[2],  t03 = tf[3];
    float t10 = tf[4],  t11 = tf[5],  t12 = tf[6],  t13 = tf[7];
    float t20 = tf[8],  t21 = tf[9],  t22 = tf[10], t23 = tf[11];

    int ns = g.nh * NVS;
    float fnh1 = (float)(g.nh - 1);
    double lsum = 0.0;

    for (int s = threadIdx.x; s < ns; s += blockDim.x) {
        int i = s / NVS;
        int j = s - i * NVS;
        float dxv = ((float)i / fnh1) * g.len;
        float dyv = ((float)j / 9.0f) * 0.5f;

        float px = g.cdx * dxv + g.cux * dyv + g.p0x;
        float py = g.cdy * dxv + g.cuy * dyv + g.p0y;
        float pz = g.cdz * dxv + g.cuz * dyv + g.p0z;

        float w1 = k20 * px + k21 * py + k22 * pz;
        float u1 = (k00 * px + k01 * py + k02 * pz) / w1;
        float v1 = (k10 * px + k11 * py + k12 * pz) / w1;
        u1 = fminf(fmaxf(u1, 0.f), 0.999999f);
        v1 = fminf(fmaxf(v1, 0.f), 0.999999f);

        float w2 = t20 * px + t21 * py + t22 * pz + t23;
        float u2 = (t00 * px + t01 * py + t02 * pz + t03) / w2;
        float v2 = (t10 * px + t11 * py + t12 * pz + t13) / w2;
        u2 = fminf(fmaxf(u2, 0.f), 0.999999f);
        v2 = fminf(fmaxf(v2, 0.f), 0.999999f);

        float s1r, s1g, s1b, s2r, s2g, s2b;
        if constexpr (PACKED) {
            bilinear3h((const uint2*)img1, u1, v1, s1r, s1g, s1b);
            bilinear3h((const uint2*)img2, u2, v2, s2r, s2g, s2b);
        } else {
            bilinear3((const float*)img1, u1, v1, s1r, s1g, s1b);
            bilinear3((const float*)img2, u2, v2, s2r, s2g, s2b);
        }

        float dr = s1r - s2r, dg = s1g - s2g, db = s1b - s2b;
        lsum += (double)(dr * dr) + (double)(dg * dg) + (double)(db * db);
    }

    double tot = block_reduce_d(lsum);
    if (threadIdx.x == 0) sim_part[blockIdx.x] = tot;
}

// ---------------------------------------------------------------------------
// finalize: deterministic reduction of partials, write 3 outputs
// ---------------------------------------------------------------------------
__global__ __launch_bounds__(256) void finalize_kernel(
        const double* __restrict__ sim_part, int n_sim,
        const double* __restrict__ normal_part,
        const double* __restrict__ norz_part, int n_a,
        const unsigned long long* __restrict__ total_x,
        float* __restrict__ out, int E) {
    int tid = threadIdx.x;
    double s = 0.0;
    for (int i = tid; i < n_sim; i += 256) s += sim_part[i];
    double sim = block_reduce_d(s);

    s = 0.0;
    for (int i = tid; i < n_a; i += 256) s += normal_part[i];
    double nrm = block_reduce_d(s);

    s = 0.0;
    for (int i = tid; i < n_a; i += 256) s += norz_part[i];
    double nz = block_reduce_d(s);

    if (tid == 0) {
        double total = (double)(*total_x) * (double)NVS * 3.0;
        out[0] = (float)(sim / total);
        out[1] = (float)((nrm / (double)E) * 0.5);
        out[2] = (float)(nz / (double)E);
    }
}

// ---------------------------------------------------------------------------
extern "C" void kernel_launch(void* const* d_in, const int* in_sizes, int n_in,
                              void* d_out, int out_size, void* d_ws, size_t ws_size,
                              hipStream_t stream) {
    const float* ep  = (const float*)d_in[0];
    const float* im1 = (const float*)d_in[1];
    const float* im2 = (const float*)d_in[2];
    const float* K1  = (const float*)d_in[3];
    const float* K2  = (const float*)d_in[4];
    const float* E1  = (const float*)d_in[5];
    const float* E2  = (const float*)d_in[6];
    float* out = (float*)d_out;

    int E = in_sizes[0] / 12;
    int nA = (E + 255) / 256;

    size_t img_bytes   = (size_t)NPIX * 8;                 // fp16-RGBA per image
    size_t packed_need = 2 * img_bytes + (size_t)E * 8 + (size_t)nA * 16 + 256;
    bool packed = ws_size >= packed_need;

    char* ws = (char*)d_ws;
    uint2* p1 = (uint2*)ws;
    uint2* p2 = (uint2*)(ws + img_bytes);
    char* tail = packed ? (ws + 2 * img_bytes) : ws;

    double* sim_part    = (double*)tail;                         // E doubles
    double* normal_part = (double*)(tail + (size_t)E * 8);       // nA doubles
    double* norz_part   = normal_part + nA;                      // nA doubles
    unsigned long long* total_x = (unsigned long long*)(norz_part + nA);
    float* tf = (float*)(total_x + 1);                           // 16 floats

    setup_kernel<<<1, 64, 0, stream>>>(K2, E1, E2, tf, total_x);
    edge_kernel<<<nA, 256, 0, stream>>>(ep, E, normal_part, norz_part, total_x);
    if (packed) {
        repack_kernel<<<2048, 256, 0, stream>>>(im1, im2, p1, p2);
        sample_kernel_t<true><<<E, 256, 0, stream>>>(ep, (const void*)p1, (const void*)p2,
                                                     K1, tf, sim_part);
    } else {
        sample_kernel_t<false><<<E, 256, 0, stream>>>(ep, (const void*)im1, (const void*)im2,
                                                      K1, tf, sim_part);
    }
    finalize_kernel<<<1, 256, 0, stream>>>(sim_part, E, normal_part, norz_part, nA,
                                           total_x, out, E);
}

// Round 4
// 92.300 us; speedup vs baseline: 2.0083x; 1.1820x over previous
//
#include <hip/hip_runtime.h>

// ---------------------------------------------------------------------------
// LModel15: edge sampling + bilinear similarity loss (MI355X / gfx950)
// Outputs: [similarity_loss, normal_loss, normalization_loss] (3x fp32)
// R4: R3 (R11G11B10 4B/pixel pack) with compile fix: clang ext_vector for
//     __builtin_nontemporal_load (HIP float4 is a class type -> rejected).
// ---------------------------------------------------------------------------

constexpr int NVS   = 10;     // NV samples along 'up'
constexpr int IMG_H = 2000;
constexpr int IMG_W = 3000;
constexpr int NPIX  = IMG_H * IMG_W;

typedef float  fx4 __attribute__((ext_vector_type(4)));
typedef unsigned ux4 __attribute__((ext_vector_type(4)));

struct Geom {
    float p0x, p0y, p0z;
    float p1x, p1y, p1z;
    float p2x, p2y, p2z;
    float p3x, p3y, p3z;
    float cdx, cdy, cdz;   // cur_dir (normalized)
    float cnx, cny, cnz;   // cur_normal (normalized, flipped)
    float cux, cuy, cuz;   // cur_up (normalized)
    float len;             // cur_length
    int   nh;
};

__device__ __forceinline__ Geom compute_geom(const float* __restrict__ ep, int e) {
    Geom g;
    const float* p = ep + (size_t)e * 12;
    g.p0x = p[0];  g.p0y = p[1];  g.p0z = p[2];
    g.p1x = p[3];  g.p1y = p[4];  g.p1z = p[5];
    g.p2x = p[6];  g.p2y = p[7];  g.p2z = p[8];
    g.p3x = p[9];  g.p3y = p[10]; g.p3z = p[11];

    float dx = g.p1x - g.p0x, dy = g.p1y - g.p0y, dz = g.p1z - g.p0z;
    float ax = dx + 1e-6f, ay = dy + 1e-6f, az = dz + 1e-6f;
    g.len = sqrtf(ax * ax + ay * ay + az * az);
    g.cdx = dx / g.len; g.cdy = dy / g.len; g.cdz = dz / g.len;

    float ndx = g.p3x - g.p1x, ndy = g.p3y - g.p1y, ndz = g.p3z - g.p1z;
    float cnx = g.cdy * ndz - g.cdz * ndy;
    float cny = g.cdz * ndx - g.cdx * ndz;
    float cnz = g.cdx * ndy - g.cdy * ndx;
    float n1 = sqrtf(cnx * cnx + cny * cny + cnz * cnz) + 1e-8f;
    cnx /= n1; cny /= n1; cnz /= n1;
    if (cnz > 0.f) { cnx = -cnx; cny = -cny; cnz = -cnz; }
    g.cnx = cnx; g.cny = cny; g.cnz = cnz;

    float cux = cny * g.cdz - cnz * g.cdy;
    float cuy = cnz * g.cdx - cnx * g.cdz;
    float cuz = cnx * g.cdy - cny * g.cdx;
    float n2 = sqrtf(cux * cux + cuy * cuy + cuz * cuz) + 1e-8f;
    g.cux = cux / n2; g.cuy = cuy / n2; g.cuz = cuz / n2;

    int nh = (int)floorf(g.len / 0.05f);
    g.nh = nh < 2 ? 2 : (nh > 1000 ? 1000 : nh);
    return g;
}

__device__ __forceinline__ double block_reduce_d(double v) {
    __shared__ double sh[256];
    int tid = threadIdx.x;
    sh[tid] = v;
    __syncthreads();
    for (int s = 128; s > 0; s >>= 1) {
        if (tid < s) sh[tid] += sh[tid + s];
        __syncthreads();
    }
    double r = sh[0];
    __syncthreads();
    return r;
}

// ---------------------------------------------------------------------------
// setup: zero counters, compute transform = K2h @ E2 @ inv(E1) (double, GJ)
// ---------------------------------------------------------------------------
__global__ void setup_kernel(const float* __restrict__ K2,
                             const float* __restrict__ E1,
                             const float* __restrict__ E2,
                             float* __restrict__ tf,
                             unsigned long long* __restrict__ total_x) {
    if (threadIdx.x != 0 || blockIdx.x != 0) return;
    *total_x = 0ull;

    double a[4][8];
    for (int r = 0; r < 4; ++r)
        for (int c = 0; c < 4; ++c) {
            a[r][c] = (double)E1[r * 4 + c];
            a[r][4 + c] = (r == c) ? 1.0 : 0.0;
        }
    for (int col = 0; col < 4; ++col) {
        int piv = col; double best = fabs(a[col][col]);
        for (int r = col + 1; r < 4; ++r) {
            double t = fabs(a[r][col]);
            if (t > best) { best = t; piv = r; }
        }
        if (piv != col)
            for (int c = 0; c < 8; ++c) { double t = a[col][c]; a[col][c] = a[piv][c]; a[piv][c] = t; }
        double d = a[col][col];
        for (int c = 0; c < 8; ++c) a[col][c] /= d;
        for (int r = 0; r < 4; ++r) {
            if (r == col) continue;
            double f = a[r][col];
            for (int c = 0; c < 8; ++c) a[r][c] -= f * a[col][c];
        }
    }
    double inv1[4][4];
    for (int r = 0; r < 4; ++r)
        for (int c = 0; c < 4; ++c) inv1[r][c] = a[r][4 + c];

    double k2h[4][4];
    for (int r = 0; r < 4; ++r)
        for (int c = 0; c < 4; ++c) k2h[r][c] = (r == c) ? 1.0 : 0.0;
    for (int r = 0; r < 3; ++r)
        for (int c = 0; c < 3; ++c) k2h[r][c] = (double)K2[r * 3 + c];

    double m1[4][4];
    for (int r = 0; r < 4; ++r)
        for (int c = 0; c < 4; ++c) {
            double s = 0.0;
            for (int k = 0; k < 4; ++k) s += (double)E2[r * 4 + k] * inv1[k][c];
            m1[r][c] = s;
        }
    for (int r = 0; r < 4; ++r)
        for (int c = 0; c < 4; ++c) {
            double s = 0.0;
            for (int k = 0; k < 4; ++k) s += k2h[r][k] * m1[k][c];
            tf[r * 4 + c] = (float)s;
        }
}

// ---------------------------------------------------------------------------
// per-edge losses + total_x
// ---------------------------------------------------------------------------
__global__ __launch_bounds__(256) void edge_kernel(
        const float* __restrict__ ep, int E,
        double* __restrict__ normal_part,
        double* __restrict__ norz_part,
        unsigned long long* __restrict__ total_x) {
    int e = blockIdx.x * blockDim.x + threadIdx.x;
    double t1 = 0.0, t2 = 0.0;
    if (e < E) {
        Geom g = compute_geom(ep, e);
        float pdx = g.p0x - g.p2x, pdy = g.p0y - g.p2y, pdz = g.p0z - g.p2z;
        float pnx = pdy * g.cdz - pdz * g.cdy;
        float pny = pdz * g.cdx - pdx * g.cdz;
        float pnz = pdx * g.cdy - pdy * g.cdx;
        float n = sqrtf(pnx * pnx + pny * pny + pnz * pnz) + 1e-8f;
        pnx /= n; pny /= n; pnz /= n;
        float dotn = g.cnx * pnx + g.cny * pny + g.cnz * pnz;
        t1 = (double)(1.0f - dotn);

        float ox = g.p0y * g.p1z - g.p0z * g.p1y;
        float oy = g.p0z * g.p1x - g.p0x * g.p1z;
        float oz = g.p0x * g.p1y - g.p0y * g.p1x;
        float no = sqrtf(ox * ox + oy * oy + oz * oz) + 1e-8f;
        ox /= no; oy /= no; oz /= no;
        float snp = fminf(fabsf(g.cux * ox + g.cuy * oy + g.cuz * oz), 0.5f);
        t2 = (double)(1.0f - snp / 0.5f);

        atomicAdd(total_x, (unsigned long long)g.nh);
    }
    double s1 = block_reduce_d(t1);
    double s2 = block_reduce_d(t2);
    if (threadIdx.x == 0) {
        normal_part[blockIdx.x] = s1;
        norz_part[blockIdx.x]   = s2;
    }
}

// ---------------------------------------------------------------------------
// pack helpers: R11G11B10 fixed point, values in [0,1)
// ---------------------------------------------------------------------------
__device__ __forceinline__ unsigned pack_rgb(float r, float g, float b) {
    unsigned ri = (unsigned)__float2int_rn(r * 2047.0f) & 2047u;
    unsigned gi = (unsigned)__float2int_rn(g * 2047.0f) & 2047u;
    unsigned bi = (unsigned)__float2int_rn(b * 1023.0f) & 1023u;
    return ri | (gi << 11) | (bi << 22);
}

// ---------------------------------------------------------------------------
// repack: CHW fp32 (3 planes) -> 4B/pixel packed. One quad (4 px) per thread.
// ---------------------------------------------------------------------------
__global__ __launch_bounds__(256) void repack_kernel(
        const float* __restrict__ img1, const float* __restrict__ img2,
        unsigned* __restrict__ o1, unsigned* __restrict__ o2) {
    const int nq = NPIX / 4;  // quads per image
    int idx = blockIdx.x * blockDim.x + threadIdx.x;
    if (idx >= 2 * nq) return;
    const float* img;
    unsigned* out;
    int q;
    if (idx < nq) { img = img1; out = o1; q = idx; }
    else          { img = img2; out = o2; q = idx - nq; }

    fx4 r = __builtin_nontemporal_load(reinterpret_cast<const fx4*>(img) + q);
    fx4 g = __builtin_nontemporal_load(reinterpret_cast<const fx4*>(img + NPIX) + q);
    fx4 b = __builtin_nontemporal_load(reinterpret_cast<const fx4*>(img + 2 * (size_t)NPIX) + q);
    ux4 o;
    o.x = pack_rgb(r.x, g.x, b.x);
    o.y = pack_rgb(r.y, g.y, b.y);
    o.z = pack_rgb(r.z, g.z, b.z);
    o.w = pack_rgb(r.w, g.w, b.w);
    reinterpret_cast<ux4*>(out)[q] = o;
}

// ---------------------------------------------------------------------------
// bilinear sample of packed R11G11B10 image: 4x 4B gathers
// ---------------------------------------------------------------------------
__device__ __forceinline__ void bilinear3p(const unsigned* __restrict__ img,
                                           float u, float v,
                                           float& r, float& g, float& b) {
    const float INV2047 = 1.0f / 2047.0f;
    const float INV1023 = 1.0f / 1023.0f;
    float x = u * (float)IMG_W - 0.5f;
    float y = v * (float)IMG_H - 0.5f;
    float x0 = floorf(x), y0 = floorf(y);
    float wx = x - x0, wy = y - y0;
    int x0i = (int)x0; x0i = x0i < 0 ? 0 : (x0i > IMG_W - 1 ? IMG_W - 1 : x0i);
    int x1i = x0i + 1; x1i = x1i > IMG_W - 1 ? IMG_W - 1 : x1i;
    int y0i = (int)y0; y0i = y0i < 0 ? 0 : (y0i > IMG_H - 1 ? IMG_H - 1 : y0i);
    int y1i = y0i + 1; y1i = y1i > IMG_H - 1 ? IMG_H - 1 : y1i;
    float w00 = (1.f - wx) * (1.f - wy);
    float w10 = wx * (1.f - wy);
    float w01 = (1.f - wx) * wy;
    float w11 = wx * wy;

    unsigned t00 = img[(size_t)y0i * IMG_W + x0i];
    unsigned t10 = img[(size_t)y0i * IMG_W + x1i];
    unsigned t01 = img[(size_t)y1i * IMG_W + x0i];
    unsigned t11 = img[(size_t)y1i * IMG_W + x1i];

    float racc = 0.f, gacc = 0.f, bacc = 0.f;
    auto acc = [&](unsigned t, float w) {
        racc += w * (float)(t & 2047u);
        gacc += w * (float)((t >> 11) & 2047u);
        bacc += w * (float)(t >> 22);
    };
    acc(t00, w00); acc(t10, w10); acc(t01, w01); acc(t11, w11);
    r = racc * INV2047; g = gacc * INV2047; b = bacc * INV1023;
}

// fp32 CHW fallback (used only when ws is too small to hold packed images)
__device__ __forceinline__ void bilinear3(const float* __restrict__ img,
                                          float u, float v,
                                          float& r, float& g, float& b) {
    float x = u * (float)IMG_W - 0.5f;
    float y = v * (float)IMG_H - 0.5f;
    float x0 = floorf(x), y0 = floorf(y);
    float wx = x - x0, wy = y - y0;
    int x0i = (int)x0; x0i = x0i < 0 ? 0 : (x0i > IMG_W - 1 ? IMG_W - 1 : x0i);
    int x1i = x0i + 1; x1i = x1i > IMG_W - 1 ? IMG_W - 1 : x1i;
    int y0i = (int)y0; y0i = y0i < 0 ? 0 : (y0i > IMG_H - 1 ? IMG_H - 1 : y0i);
    int y1i = y0i + 1; y1i = y1i > IMG_H - 1 ? IMG_H - 1 : y1i;
    float w00 = (1.f - wx) * (1.f - wy);
    float w10 = wx * (1.f - wy);
    float w01 = (1.f - wx) * wy;
    float w11 = wx * wy;
    float out[3];
#pragma unroll
    for (int c = 0; c < 3; ++c) {
        const float* p = img + (size_t)c * NPIX;
        float v00 = p[(size_t)y0i * IMG_W + x0i];
        float v10 = p[(size_t)y0i * IMG_W + x1i];
        float v01 = p[(size_t)y1i * IMG_W + x0i];
        float v11 = p[(size_t)y1i * IMG_W + x1i];
        out[c] = v00 * w00 + v10 * w10 + v01 * w01 + v11 * w11;
    }
    r = out[0]; g = out[1]; b = out[2];
}

// ---------------------------------------------------------------------------
// main sampling kernels: one block per edge
// ---------------------------------------------------------------------------
template <bool PACKED>
__global__ __launch_bounds__(256) void sample_kernel_t(
        const float* __restrict__ ep,
        const void* __restrict__ img1,
        const void* __restrict__ img2,
        const float* __restrict__ K1,
        const float* __restrict__ tf,
        double* __restrict__ sim_part) {
    int e = blockIdx.x;
    Geom g = compute_geom(ep, e);

    float k00 = K1[0], k01 = K1[1], k02 = K1[2];
    float k10 = K1[3], k11 = K1[4], k12 = K1[5];
    float k20 = K1[6], k21 = K1[7], k22 = K1[8];
    float t00 = tf[0],  t01 = tf[1],  t02 = tf[2],  t03 = tf[3];
    float t10 = tf[4],  t11 = tf[5],  t12 = tf[6],  t13 = tf[7];
    float t20 = tf[8],  t21 = tf[9],  t22 = tf[10], t23 = tf[11];

    int ns = g.nh * NVS;
    float fnh1 = (float)(g.nh - 1);
    double lsum = 0.0;

    for (int s = threadIdx.x; s < ns; s += blockDim.x) {
        int i = s / NVS;
        int j = s - i * NVS;
        float dxv = ((float)i / fnh1) * g.len;
        float dyv = ((float)j / 9.0f) * 0.5f;

        float px = g.cdx * dxv + g.cux * dyv + g.p0x;
        float py = g.cdy * dxv + g.cuy * dyv + g.p0y;
        float pz = g.cdz * dxv + g.cuz * dyv + g.p0z;

        float w1 = k20 * px + k21 * py + k22 * pz;
        float u1 = (k00 * px + k01 * py + k02 * pz) / w1;
        float v1 = (k10 * px + k11 * py + k12 * pz) / w1;
        u1 = fminf(fmaxf(u1, 0.f), 0.999999f);
        v1 = fminf(fmaxf(v1, 0.f), 0.999999f);

        float w2 = t20 * px + t21 * py + t22 * pz + t23;
        float u2 = (t00 * px + t01 * py + t02 * pz + t03) / w2;
        float v2 = (t10 * px + t11 * py + t12 * pz + t13) / w2;
        u2 = fminf(fmaxf(u2, 0.f), 0.999999f);
        v2 = fminf(fmaxf(v2, 0.f), 0.999999f);

        float s1r, s1g, s1b, s2r, s2g, s2b;
        if constexpr (PACKED) {
            bilinear3p((const unsigned*)img1, u1, v1, s1r, s1g, s1b);
            bilinear3p((const unsigned*)img2, u2, v2, s2r, s2g, s2b);
        } else {
            bilinear3((const float*)img1, u1, v1, s1r, s1g, s1b);
            bilinear3((const float*)img2, u2, v2, s2r, s2g, s2b);
        }

        float dr = s1r - s2r, dg = s1g - s2g, db = s1b - s2b;
        lsum += (double)(dr * dr) + (double)(dg * dg) + (double)(db * db);
    }

    double tot = block_reduce_d(lsum);
    if (threadIdx.x == 0) sim_part[blockIdx.x] = tot;
}

// ---------------------------------------------------------------------------
// finalize: deterministic reduction of partials, write 3 outputs
// ---------------------------------------------------------------------------
__global__ __launch_bounds__(256) void finalize_kernel(
        const double* __restrict__ sim_part, int n_sim,
        const double* __restrict__ normal_part,
        const double* __restrict__ norz_part, int n_a,
        const unsigned long long* __restrict__ total_x,
        float* __restrict__ out, int E) {
    int tid = threadIdx.x;
    double s = 0.0;
    for (int i = tid; i < n_sim; i += 256) s += sim_part[i];
    double sim = block_reduce_d(s);

    s = 0.0;
    for (int i = tid; i < n_a; i += 256) s += normal_part[i];
    double nrm = block_reduce_d(s);

    s = 0.0;
    for (int i = tid; i < n_a; i += 256) s += norz_part[i];
    double nz = block_reduce_d(s);

    if (tid == 0) {
        double total = (double)(*total_x) * (double)NVS * 3.0;
        out[0] = (float)(sim / total);
        out[1] = (float)((nrm / (double)E) * 0.5);
        out[2] = (float)(nz / (double)E);
    }
}

// ---------------------------------------------------------------------------
extern "C" void kernel_launch(void* const* d_in, const int* in_sizes, int n_in,
                              void* d_out, int out_size, void* d_ws, size_t ws_size,
                              hipStream_t stream) {
    const float* ep  = (const float*)d_in[0];
    const float* im1 = (const float*)d_in[1];
    const float* im2 = (const float*)d_in[2];
    const float* K1  = (const float*)d_in[3];
    const float* K2  = (const float*)d_in[4];
    const float* E1  = (const float*)d_in[5];
    const float* E2  = (const float*)d_in[6];
    float* out = (float*)d_out;

    int E = in_sizes[0] / 12;
    int nA = (E + 255) / 256;

    size_t img_bytes   = (size_t)NPIX * 4;                 // packed per image
    size_t packed_need = 2 * img_bytes + (size_t)E * 8 + (size_t)nA * 16 + 256;
    bool packed = ws_size >= packed_need;

    char* ws = (char*)d_ws;
    unsigned* p1 = (unsigned*)ws;
    unsigned* p2 = (unsigned*)(ws + img_bytes);
    char* tail = packed ? (ws + 2 * img_bytes) : ws;

    double* sim_part    = (double*)tail;                         // E doubles
    double* normal_part = (double*)(tail + (size_t)E * 8);       // nA doubles
    double* norz_part   = normal_part + nA;                      // nA doubles
    unsigned long long* total_x = (unsigned long long*)(norz_part + nA);
    float* tf = (float*)(total_x + 1);                           // 16 floats

    setup_kernel<<<1, 64, 0, stream>>>(K2, E1, E2, tf, total_x);
    edge_kernel<<<nA, 256, 0, stream>>>(ep, E, normal_part, norz_part, total_x);
    if (packed) {
        const int nq2 = 2 * (NPIX / 4);
        repack_kernel<<<(nq2 + 255) / 256, 256, 0, stream>>>(im1, im2, p1, p2);
        sample_kernel_t<true><<<E, 256, 0, stream>>>(ep, (const void*)p1, (const void*)p2,
                                                     K1, tf, sim_part);
    } else {
        sample_kernel_t<false><<<E, 256, 0, stream>>>(ep, (const void*)im1, (const void*)im2,
                                                      K1, tf, sim_part);
    }
    finalize_kernel<<<1, 256, 0, stream>>>(sim_part, E, normal_part, norz_part, nA,
                                           total_x, out, E);
}